// Round 12
// baseline (1075.413 us; speedup 1.0000x reference)
//
#include <hip/hip_runtime.h>
#include <hip/hip_bf16.h>

typedef __attribute__((ext_vector_type(8))) short short8;
typedef __attribute__((ext_vector_type(4))) float float4v;

#if __has_builtin(__builtin_amdgcn_sdot4)
#define DOT4(a, b, c) __builtin_amdgcn_sdot4((int)(a), (int)(b), (c), false)
#else
__device__ __forceinline__ int dot4_(int a, int b, int c) {
  c += (int)(signed char)(a) * (int)(signed char)(b);
  c += (int)(signed char)(a >> 8) * (int)(signed char)(b >> 8);
  c += (int)(signed char)(a >> 16) * (int)(signed char)(b >> 16);
  c += (a >> 24) * (b >> 24);
  return c;
}
#define DOT4(a, b, c) dot4_((int)(a), (int)(b), (c))
#endif

__device__ __forceinline__ float sigmoidf_(float x) {
  return __fdividef(1.f, 1.f + __expf(-x));
}
__device__ __forceinline__ float tanhf_(float x) {
  float e = __expf(2.f * x);
  return 1.f - __fdividef(2.f, e + 1.f);
}
__device__ __forceinline__ float bflo(unsigned int v) {
  return __uint_as_float(v << 16);
}
__device__ __forceinline__ float bfhi(unsigned int v) {
  return __uint_as_float(v & 0xffff0000u);
}
// barrier that waits only LDS counts (h ordering) -- skips the vmcnt(0) drain
__device__ __forceinline__ void barrier_lgkm() {
  asm volatile("s_waitcnt lgkmcnt(0)\n\ts_barrier" ::: "memory");
}

// quad (4-lane) butterflies via DPP quad_perm (VALU, not DS pipe)
template <int CTRL>
__device__ __forceinline__ int qadd_i(int v) {
  return v + __builtin_amdgcn_update_dpp(0, v, CTRL, 0xF, 0xF, true);
}
#define XOR1 0xB1  // quad_perm [1,0,3,2]
#define XOR2 0x4E  // quad_perm [2,3,0,1]

__device__ __forceinline__ unsigned int pack4_(float4 v, float inv) {
  int b0 = (int)rintf(v.x * inv), b1 = (int)rintf(v.y * inv);
  int b2 = (int)rintf(v.z * inv), b3 = (int)rintf(v.w * inv);
  return (unsigned int)((b0 & 0xff) | ((b1 & 0xff) << 8) | ((b2 & 0xff) << 16) |
                        ((b3 & 0xff) << 24));
}

// ---------------------------------------------------------------------------
// Kernel Q: one-time int8 weight quantization. One wave per gate row.
// ---------------------------------------------------------------------------
__global__ __launch_bounds__(256) void wquant_kernel(
    const float* __restrict__ whh_f, const float* __restrict__ whh_b,
    unsigned int* __restrict__ wq, float* __restrict__ wsc) {
  const int wave_g = blockIdx.x * 4 + (threadIdx.x >> 6);
  const int lane = threadIdx.x & 63;
  const int dir = wave_g >> 10, row = wave_g & 1023;
  const float* __restrict__ src = (dir ? whh_b : whh_f) + (size_t)row * 256;
  float4 v = ((const float4*)src)[lane];
  float mx = fmaxf(fmaxf(fabsf(v.x), fabsf(v.y)), fmaxf(fabsf(v.z), fabsf(v.w)));
#pragma unroll
  for (int k = 32; k >= 1; k >>= 1) mx = fmaxf(mx, __shfl_xor(mx, k, 64));
  float inv = (mx > 0.f) ? __fdividef(127.f, mx) : 0.f;
  wq[(size_t)wave_g * 64 + lane] = pack4_(v, inv);
  if (lane == 0) wsc[wave_g] = (mx > 0.f) ? (mx / (127.f * 127.f)) : 0.f;
}

// ---------------------------------------------------------------------------
// Kernel A: projected embedding tables. M-tile 128.
// Stored at out[m*2048 + dir*1024 + u*4 + gate]  ([row][dir][unit][i,f,g,o]).
// ---------------------------------------------------------------------------
__global__ __launch_bounds__(256) void proj_gemm(
    const float* __restrict__ A, int rowsA, int Kdim, int col_off,
    const float* __restrict__ wf, const float* __restrict__ wb,
    const float* __restrict__ bf1, const float* __restrict__ bf2,
    const float* __restrict__ bb1, const float* __restrict__ bb2,
    __hip_bfloat16* __restrict__ out, int add_bias) {
  __shared__ __align__(16) __hip_bfloat16 As[128][40];
  __shared__ __align__(16) __hip_bfloat16 Bs[256][40];
  const int tid = threadIdx.x;
  const int m0 = blockIdx.x * 128, n0 = blockIdx.y * 256;
  const int lane = tid & 63, wave = tid >> 6;
  const int quad = lane >> 4, lm = lane & 15;
  float4v acc[2][16] = {};
  const int ksteps = (Kdim + 31) >> 5;
  const int r2 = tid >> 1, cbase = (tid & 1) << 4;
  const int rb = tid >> 4, cb = (tid & 15) * 2;
  for (int ks = 0; ks < ksteps; ++ks) {
    const int k0 = ks << 5;
#pragma unroll
    for (int e2 = 0; e2 < 8; ++e2) {
      int kk = k0 + cbase + 2 * e2;
      float b0 = 0.f, b1 = 0.f;
      if (m0 + r2 < rowsA && kk < Kdim) {
        float2 v = *(const float2*)(A + (size_t)(m0 + r2) * Kdim + kk);
        b0 = v.x;
        b1 = v.y;
      }
      As[r2][cbase + 2 * e2] = __float2bfloat16(b0);
      As[r2][cbase + 2 * e2 + 1] = __float2bfloat16(b1);
    }
#pragma unroll
    for (int j = 0; j < 16; ++j) {
      int n = n0 + rb + 16 * j;
      const float* __restrict__ wrow =
          (n < 1024) ? (wf + n * 450 + col_off) : (wb + (n - 1024) * 450 + col_off);
      int kk = k0 + cb;
      float b0 = 0.f, b1 = 0.f;
      if (kk < Kdim) {
        float2 v = *(const float2*)(wrow + kk);
        b0 = v.x;
        b1 = v.y;
      }
      Bs[rb + 16 * j][cb] = __float2bfloat16(b0);
      Bs[rb + 16 * j][cb + 1] = __float2bfloat16(b1);
    }
    __syncthreads();
    short8 af0 = *(const short8*)(&As[wave * 32 + lm][quad * 8]);
    short8 af1 = *(const short8*)(&As[wave * 32 + 16 + lm][quad * 8]);
#pragma unroll
    for (int t = 0; t < 16; ++t) {
      short8 bf = *(const short8*)(&Bs[t * 16 + lm][quad * 8]);
      acc[0][t] = __builtin_amdgcn_mfma_f32_16x16x32_bf16(af0, bf, acc[0][t], 0, 0, 0);
      acc[1][t] = __builtin_amdgcn_mfma_f32_16x16x32_bf16(af1, bf, acc[1][t], 0, 0, 0);
    }
    __syncthreads();
  }
#pragma unroll
  for (int mg = 0; mg < 2; ++mg) {
#pragma unroll
    for (int t = 0; t < 16; ++t) {
#pragma unroll
      for (int rr = 0; rr < 4; ++rr) {
        int m = m0 + wave * 32 + mg * 16 + quad * 4 + rr;
        int col = n0 + t * 16 + lm;
        if (m < rowsA) {
          float v = acc[mg][t][rr];
          if (add_bias)
            v += (col < 1024) ? (bf1[col] + bf2[col]) : (bb1[col - 1024] + bb2[col - 1024]);
          int dir = col >> 10, rq = col & 1023;
          int gate = rq >> 8, u = rq & 255;
          out[m * 2048 + dir * 1024 + u * 4 + gate] = __float2bfloat16(v);
        }
      }
    }
  }
}

// ---------------------------------------------------------------------------
// Kernel B: BiLSTM recurrence, int8 dot4, 256 threads/chain (4 waves).
// 12 rows int8 in VGPRs (192 regs, PINNED via opaque asm so the compiler
// cannot sink the loads into the loop -- R11 showed it rematerialized them
// as ~48 L2 loads/step at 1 wave/SIMD = unhidden latency), 4 rows in
// conflict-free LDS planes. Per-step barrier waits lgkmcnt only.
// ---------------------------------------------------------------------------
__global__ __launch_bounds__(256) void lstm_kernel(
    const unsigned int* __restrict__ wq, const float* __restrict__ wsc,
    const int* __restrict__ x, const int* __restrict__ ptags, const int* __restrict__ gtags,
    const char* __restrict__ char_proj, const char* __restrict__ pin_proj,
    const char* __restrict__ tag_proj, __hip_bfloat16* __restrict__ h_out) {
  extern __shared__ __align__(16) char smem[];
  uint4* wlds = (uint4*)smem;                              // 16*256*16 = 65536
  __hip_bfloat16* hist = (__hip_bfloat16*)(smem + 65536);  // 32*256*2 = 16384
  signed char* hb = (signed char*)(smem + 81920);          // 2*256 = 512

  const int tid = threadIdx.x;
  const int q = tid >> 2, e = tid & 3;
  const int chain = blockIdx.x;
  const int dir = chain >> 7;
  const int b = chain & 127;
  const int boff = b * 512;

  if (tid < 32) ((int4*)hb)[tid] = make_int4(0, 0, 0, 0);

  // ---- load pre-quantized weights (12 rows -> VGPR, 4 rows -> LDS planes) ----
  const unsigned int* __restrict__ wqd = wq + (size_t)dir * 65536;
  const float* __restrict__ wscd = wsc + dir * 1024;
  unsigned int Wreg[12][16];
  float sc4[4];
#pragma unroll
  for (int rr = 0; rr < 16; ++rr) {
    const int grow = (rr & 3) * 256 + 4 * q + (rr >> 2);
    const uint4* __restrict__ srcp = (const uint4*)(wqd + grow * 64 + e * 16);
    if ((rr >> 2) == e) sc4[rr & 3] = wscd[grow];
    if (rr < 12) {
      uint4 a = srcp[0], b4 = srcp[1], c4 = srcp[2], d4 = srcp[3];
      Wreg[rr][0] = a.x;  Wreg[rr][1] = a.y;  Wreg[rr][2] = a.z;  Wreg[rr][3] = a.w;
      Wreg[rr][4] = b4.x; Wreg[rr][5] = b4.y; Wreg[rr][6] = b4.z; Wreg[rr][7] = b4.w;
      Wreg[rr][8] = c4.x; Wreg[rr][9] = c4.y; Wreg[rr][10] = c4.z; Wreg[rr][11] = c4.w;
      Wreg[rr][12] = d4.x; Wreg[rr][13] = d4.y; Wreg[rr][14] = d4.z; Wreg[rr][15] = d4.w;
    } else {
#pragma unroll
      for (int c = 0; c < 4; ++c) wlds[((rr - 12) * 4 + c) * 256 + tid] = srcp[c];
    }
  }
  // PIN: opaque asm makes these values non-rematerializable -> they stay in
  // VGPRs across the whole loop instead of being re-loaded from L2 each step.
#pragma unroll
  for (int rr = 0; rr < 12; ++rr)
#pragma unroll
    for (int k = 0; k < 16; ++k) asm volatile("" : "+v"(Wreg[rr][k]));
#pragma unroll
  for (int g = 0; g < 4; ++g) asm volatile("" : "+v"(sc4[g]));
  __syncthreads();

  const int myu = tid;
  const int pre_off = dir * 2048 + myu * 8;
  float cst = 0.f;
  const uint4* wbase = wlds + tid;  // + (p*4+c)*256 becomes a DS imm offset

  // prefetch rotation: indices 2 steps ahead (scalar), gathers 1 step ahead
  int t_cur = dir ? 511 : 0;
  int t_nxt = dir ? 510 : 1;
  int xc = x[boff + t_cur], pc_i = ptags[boff + t_cur], gc_i = gtags[boff + t_cur];
  uint2 vc = *(const uint2*)(char_proj + (size_t)xc * 4096 + pre_off);
  uint2 vp = *(const uint2*)(pin_proj + (size_t)pc_i * 4096 + pre_off);
  uint2 vg = *(const uint2*)(tag_proj + (size_t)gc_i * 4096 + pre_off);
  int xn = x[boff + t_nxt], pn = ptags[boff + t_nxt], gn = gtags[boff + t_nxt];

  for (int s = 0; s < 512; ++s) {
    const int t = t_cur;
    const uint2 cv = vc, pv = vp, gv = vg;
    const int t_fut = dir ? (t_nxt > 0 ? t_nxt - 1 : 0) : (t_nxt < 511 ? t_nxt + 1 : 511);
    vc = *(const uint2*)(char_proj + (size_t)xn * 4096 + pre_off);
    vp = *(const uint2*)(pin_proj + (size_t)pn * 4096 + pre_off);
    vg = *(const uint2*)(tag_proj + (size_t)gn * 4096 + pre_off);
    xn = x[boff + t_fut];
    pn = ptags[boff + t_fut];
    gn = gtags[boff + t_fut];

    const signed char* hbase = hb + (s & 1) * 256 + e * 64;
    int acc[16] = {0, 0, 0, 0, 0, 0, 0, 0, 0, 0, 0, 0, 0, 0, 0, 0};
#pragma unroll
    for (int c = 0; c < 4; ++c) {
      uint4 H = *(const uint4*)(hbase + c * 16);
#pragma unroll
      for (int rr = 0; rr < 12; ++rr) {
        acc[rr] = DOT4(Wreg[rr][4 * c + 0], H.x, acc[rr]);
        acc[rr] = DOT4(Wreg[rr][4 * c + 1], H.y, acc[rr]);
        acc[rr] = DOT4(Wreg[rr][4 * c + 2], H.z, acc[rr]);
        acc[rr] = DOT4(Wreg[rr][4 * c + 3], H.w, acc[rr]);
      }
#pragma unroll
      for (int p = 0; p < 4; ++p) {
        uint4 wv = wbase[(p * 4 + c) * 256];
        acc[12 + p] = DOT4(wv.x, H.x, acc[12 + p]);
        acc[12 + p] = DOT4(wv.y, H.y, acc[12 + p]);
        acc[12 + p] = DOT4(wv.z, H.z, acc[12 + p]);
        acc[12 + p] = DOT4(wv.w, H.w, acc[12 + p]);
      }
    }
#pragma unroll
    for (int rr = 0; rr < 16; ++rr) {
      int v = qadd_i<XOR1>(acc[rr]);
      acc[rr] = qadd_i<XOR2>(v);
    }
    int ai = e == 0 ? acc[0] : (e == 1 ? acc[4] : (e == 2 ? acc[8] : acc[12]));
    int af = e == 0 ? acc[1] : (e == 1 ? acc[5] : (e == 2 ? acc[9] : acc[13]));
    int ag = e == 0 ? acc[2] : (e == 1 ? acc[6] : (e == 2 ? acc[10] : acc[14]));
    int ao = e == 0 ? acc[3] : (e == 1 ? acc[7] : (e == 2 ? acc[11] : acc[15]));
    float gi = bflo(cv.x) + bflo(pv.x) + bflo(gv.x) + (float)ai * sc4[0];
    float gf = bfhi(cv.x) + bfhi(pv.x) + bfhi(gv.x) + (float)af * sc4[1];
    float gg = bflo(cv.y) + bflo(pv.y) + bflo(gv.y) + (float)ag * sc4[2];
    float go = bfhi(cv.y) + bfhi(pv.y) + bfhi(gv.y) + (float)ao * sc4[3];
    cst = sigmoidf_(gf) * cst + sigmoidf_(gi) * tanhf_(gg);
    float hval = sigmoidf_(go) * tanhf_(cst);
    hb[((s + 1) & 1) * 256 + myu] = (signed char)(int)rintf(hval * 127.f);
    hist[(s & 31) * 256 + myu] = __float2bfloat16(hval);
    barrier_lgkm();
    if ((s & 15) == 15) {
      const int slotBase = (s & 31) & ~15;
      const int sBase = s - 15;
#pragma unroll
      for (int i = 0; i < 2; ++i) {
        int c = i * 256 + tid;
        int row = c >> 5;
        int col16 = c & 31;
        uint4 v = *(const uint4*)((const char*)hist + (slotBase + row) * 512 + col16 * 16);
        int step_r = sBase + row;
        int t_r = dir ? (511 - step_r) : step_r;
        *(uint4*)((char*)h_out + ((size_t)(chain * 512 + t_r) * 256) * 2 + col16 * 16) = v;
      }
    }
    t_cur = t_nxt;
    t_nxt = t_fut;
  }
}

// ---------------------------------------------------------------------------
// Kernel C: emissions GEMM. em[b*512+t][k] = Hcat[n]·w_out[k] + b_out[k]
// ---------------------------------------------------------------------------
__global__ __launch_bounds__(256) void emis_kernel(
    const __hip_bfloat16* __restrict__ h_glob, const float* __restrict__ w_out,
    const float* __restrict__ b_out, float* __restrict__ em) {
  __shared__ __align__(16) __hip_bfloat16 As[64][40];
  __shared__ __align__(16) __hip_bfloat16 Bs[32][40];
  const int tid = threadIdx.x;
  const int n0 = blockIdx.x * 64;
  const int lane = tid & 63, wave = tid >> 6, quad = lane >> 4, lm = lane & 15;
  float4v acc[2] = {};
  const int r = tid >> 2, c0 = (tid & 3) << 3;
  const int rb = tid >> 3, cb = (tid & 7) << 2;
  for (int ks = 0; ks < 16; ++ks) {
    const int j0 = ks * 32;
    const int dirk = j0 >> 8, jin = j0 & 255;
    const int n = n0 + r, bb = n >> 9, tt = n & 511;
    const uint4* src =
        (const uint4*)(h_glob + ((size_t)(dirk * 128 + bb) * 512 + tt) * 256 + jin + c0);
    *(uint4*)(&As[r][c0]) = *src;
#pragma unroll
    for (int e = 0; e < 4; ++e) {
      float v = (rb < 20) ? w_out[rb * 512 + j0 + cb + e] : 0.f;
      Bs[rb][cb + e] = __float2bfloat16(v);
    }
    __syncthreads();
    short8 af = *(const short8*)(&As[wave * 16 + lm][quad * 8]);
#pragma unroll
    for (int t2 = 0; t2 < 2; ++t2) {
      short8 bf = *(const short8*)(&Bs[t2 * 16 + lm][quad * 8]);
      acc[t2] = __builtin_amdgcn_mfma_f32_16x16x32_bf16(af, bf, acc[t2], 0, 0, 0);
    }
    __syncthreads();
  }
#pragma unroll
  for (int t2 = 0; t2 < 2; ++t2) {
#pragma unroll
    for (int rr = 0; rr < 4; ++rr) {
      int col = t2 * 16 + lm;
      if (col < 20) {
        int n = n0 + wave * 16 + quad * 4 + rr;
        em[(size_t)n * 20 + col] = acc[t2][rr] + b_out[col];
      }
    }
  }
}

// ---------------------------------------------------------------------------
// Kernel D: CRF forward NLL. 1 wave per batch element, readlane broadcast.
// ---------------------------------------------------------------------------
__global__ __launch_bounds__(64) void crf_kernel(
    const float* __restrict__ em, const int* __restrict__ y,
    const float* __restrict__ start_trans, const float* __restrict__ end_trans,
    const float* __restrict__ trans, float* __restrict__ partials) {
  const int b = blockIdx.x;
  const int lane = threadIdx.x;
  const int jj = lane < 20 ? lane : 19;
  const bool act = lane < 20;
  const float* __restrict__ emb = em + (size_t)b * 512 * 20;
  const int* __restrict__ yb = y + b * 512;

  float s_part = 0.f;
#pragma unroll
  for (int i = 0; i < 8; ++i) {
    int t = lane + 64 * i;
    int yc = yb[t];
    float v = emb[t * 20 + yc];
    v += (t == 0) ? start_trans[yc] : trans[yb[t - 1] * 20 + yc];
    s_part += v;
  }
#pragma unroll
  for (int k = 32; k >= 1; k >>= 1) s_part += __shfl_xor(s_part, k, 64);
  float score = s_part + end_trans[yb[511]];

  float ET[20];
#pragma unroll
  for (int i = 0; i < 20; ++i) ET[i] = __expf(trans[i * 20 + jj]);
  float alpha = act ? (start_trans[jj] + emb[jj]) : -1e30f;
  float P = alpha;
#pragma unroll
  for (int k = 32; k >= 1; k >>= 1) P = fmaxf(P, __shfl_xor(P, k, 64));

  float eC = emb[1 * 20 + jj];
  float eN = emb[2 * 20 + jj];
  for (int t = 1; t < 512; ++t) {
    if ((t & 15) == 0) {
      P = alpha;
#pragma unroll
      for (int k = 32; k >= 1; k >>= 1) P = fmaxf(P, __shfl_xor(P, k, 64));
    }
    float ex = __expf(alpha - P);
    float s0 = 0.f, s1 = 0.f;
#pragma unroll
    for (int i = 0; i < 20; i += 2) {
      float e0 = __int_as_float(__builtin_amdgcn_readlane(__float_as_int(ex), i));
      float e1 = __int_as_float(__builtin_amdgcn_readlane(__float_as_int(ex), i + 1));
      s0 = fmaf(e0, ET[i], s0);
      s1 = fmaf(e1, ET[i + 1], s1);
    }
    int tf = t + 2 < 512 ? t + 2 : 511;
    float eF = emb[tf * 20 + jj];
    if (act) alpha = P + __logf(s0 + s1) + eC;
    eC = eN;
    eN = eF;
  }
  float v = act ? (alpha + end_trans[jj]) : -1e30f;
  float Pz = v;
#pragma unroll
  for (int k = 32; k >= 1; k >>= 1) Pz = fmaxf(Pz, __shfl_xor(Pz, k, 64));
  float e2 = __expf(v - Pz);
#pragma unroll
  for (int k = 32; k >= 1; k >>= 1) e2 += __shfl_xor(e2, k, 64);
  float logZ = Pz + __logf(e2);
  if (lane == 0) partials[b] = logZ - score;
}

__global__ __launch_bounds__(128) void reduce_kernel(const float* __restrict__ partials,
                                                     float* __restrict__ out) {
  const int tid = threadIdx.x;
  float v = partials[tid];
#pragma unroll
  for (int k = 32; k >= 1; k >>= 1) v += __shfl_xor(v, k, 64);
  __shared__ float tmp[2];
  if ((tid & 63) == 0) tmp[tid >> 6] = v;
  __syncthreads();
  if (tid == 0) out[0] = tmp[0] + tmp[1];
}

// ---------------------------------------------------------------------------
extern "C" void kernel_launch(void* const* d_in, const int* in_sizes, int n_in,
                              void* d_out, int out_size, void* d_ws, size_t ws_size,
                              hipStream_t stream) {
  const int* x = (const int*)d_in[0];
  const int* y = (const int*)d_in[1];
  const int* pre_tags = (const int*)d_in[2];
  const int* pinyin_tags = (const int*)d_in[3];
  const float* char_emb = (const float*)d_in[5];
  const float* tag_emb = (const float*)d_in[6];
  const float* pinyin_emb = (const float*)d_in[7];
  const float* w_ih_f = (const float*)d_in[8];
  const float* w_hh_f = (const float*)d_in[9];
  const float* b_ih_f = (const float*)d_in[10];
  const float* b_hh_f = (const float*)d_in[11];
  const float* w_ih_b = (const float*)d_in[12];
  const float* w_hh_b = (const float*)d_in[13];
  const float* b_ih_b = (const float*)d_in[14];
  const float* b_hh_b = (const float*)d_in[15];
  const float* w_out = (const float*)d_in[16];
  const float* b_out = (const float*)d_in[17];
  const float* start_trans = (const float*)d_in[18];
  const float* end_trans = (const float*)d_in[19];
  const float* trans = (const float*)d_in[20];

  char* ws = (char*)d_ws;
  __hip_bfloat16* char_proj = (__hip_bfloat16*)(ws);            // 10002*2048*2 = 40968192
  __hip_bfloat16* pin_proj = (__hip_bfloat16*)(ws + 40968192);  // 500*2048*2  = 2048000
  __hip_bfloat16* tag_proj = (__hip_bfloat16*)(ws + 43016192);  // 20*2048*2   = 81920
  __hip_bfloat16* h_glob = (__hip_bfloat16*)(ws + 43098112);    // 2*128*512*256*2 = 67108864
  float* em = (float*)(ws + 110206976);                         // 65536*20*4 = 5242880
  float* partials = (float*)(ws + 115449856);                   // 128*4
  // wq/wsc live inside the em region (em is written only after lstm finishes)
  unsigned int* wq = (unsigned int*)(ws + 110206976);           // 2*1024*64*4 = 524288
  float* wsc = (float*)(ws + 110206976 + 524288);               // 2048*4

  wquant_kernel<<<512, 256, 0, stream>>>(w_hh_f, w_hh_b, wq, wsc);

  proj_gemm<<<dim3(79, 8), 256, 0, stream>>>(char_emb, 10002, 300, 0, w_ih_f, w_ih_b,
                                             nullptr, nullptr, nullptr, nullptr, char_proj, 0);
  proj_gemm<<<dim3(4, 8), 256, 0, stream>>>(pinyin_emb, 500, 100, 300, w_ih_f, w_ih_b,
                                            nullptr, nullptr, nullptr, nullptr, pin_proj, 0);
  proj_gemm<<<dim3(1, 8), 256, 0, stream>>>(tag_emb, 20, 50, 400, w_ih_f, w_ih_b,
                                            b_ih_f, b_hh_f, b_ih_b, b_hh_b, tag_proj, 1);

  const int lstm_lds = 82432;  // 65536 planes + 16384 hist + 512 hbuf
  hipFuncSetAttribute((const void*)lstm_kernel, hipFuncAttributeMaxDynamicSharedMemorySize,
                      lstm_lds);
  lstm_kernel<<<256, 256, lstm_lds, stream>>>(wq, wsc, x, pinyin_tags, pre_tags,
                                              (const char*)char_proj, (const char*)pin_proj,
                                              (const char*)tag_proj, h_glob);

  emis_kernel<<<1024, 256, 0, stream>>>(h_glob, w_out, b_out, em);
  crf_kernel<<<128, 64, 0, stream>>>(em, y, start_trans, end_trans, trans, partials);
  reduce_kernel<<<1, 128, 0, stream>>>(partials, (float*)d_out);
}

// Round 13
// 1061.429 us; speedup vs baseline: 1.0132x; 1.0132x over previous
//
#include <hip/hip_runtime.h>
#include <hip/hip_bf16.h>

typedef __attribute__((ext_vector_type(8))) short short8;
typedef __attribute__((ext_vector_type(4))) float float4v;

#if __has_builtin(__builtin_amdgcn_sdot4)
#define DOT4(a, b, c) __builtin_amdgcn_sdot4((int)(a), (int)(b), (c), false)
#else
__device__ __forceinline__ int dot4_(int a, int b, int c) {
  c += (int)(signed char)(a) * (int)(signed char)(b);
  c += (int)(signed char)(a >> 8) * (int)(signed char)(b >> 8);
  c += (int)(signed char)(a >> 16) * (int)(signed char)(b >> 16);
  c += (a >> 24) * (b >> 24);
  return c;
}
#define DOT4(a, b, c) dot4_((int)(a), (int)(b), (c))
#endif

__device__ __forceinline__ float sigmoidf_(float x) {
  return __fdividef(1.f, 1.f + __expf(-x));
}
__device__ __forceinline__ float tanhf_(float x) {
  float e = __expf(2.f * x);
  return 1.f - __fdividef(2.f, e + 1.f);
}
__device__ __forceinline__ float bflo(unsigned int v) {
  return __uint_as_float(v << 16);
}
__device__ __forceinline__ float bfhi(unsigned int v) {
  return __uint_as_float(v & 0xffff0000u);
}
// barrier that waits only LDS counts (h ordering) -- skips the vmcnt(0) drain
__device__ __forceinline__ void barrier_lgkm() {
  asm volatile("s_waitcnt lgkmcnt(0)\n\ts_barrier" ::: "memory");
}

// quad (4-lane) butterflies via DPP quad_perm (VALU, not DS pipe)
template <int CTRL>
__device__ __forceinline__ int qadd_i(int v) {
  return v + __builtin_amdgcn_update_dpp(0, v, CTRL, 0xF, 0xF, true);
}
#define XOR1 0xB1  // quad_perm [1,0,3,2]
#define XOR2 0x4E  // quad_perm [2,3,0,1]

__device__ __forceinline__ unsigned int pack4_(float4 v, float inv) {
  int b0 = (int)rintf(v.x * inv), b1 = (int)rintf(v.y * inv);
  int b2 = (int)rintf(v.z * inv), b3 = (int)rintf(v.w * inv);
  return (unsigned int)((b0 & 0xff) | ((b1 & 0xff) << 8) | ((b2 & 0xff) << 16) |
                        ((b3 & 0xff) << 24));
}

// ---------------------------------------------------------------------------
// Kernel Q: one-time int8 weight quantization. One wave per gate row.
// ---------------------------------------------------------------------------
__global__ __launch_bounds__(256) void wquant_kernel(
    const float* __restrict__ whh_f, const float* __restrict__ whh_b,
    unsigned int* __restrict__ wq, float* __restrict__ wsc) {
  const int wave_g = blockIdx.x * 4 + (threadIdx.x >> 6);
  const int lane = threadIdx.x & 63;
  const int dir = wave_g >> 10, row = wave_g & 1023;
  const float* __restrict__ src = (dir ? whh_b : whh_f) + (size_t)row * 256;
  float4 v = ((const float4*)src)[lane];
  float mx = fmaxf(fmaxf(fabsf(v.x), fabsf(v.y)), fmaxf(fabsf(v.z), fabsf(v.w)));
#pragma unroll
  for (int k = 32; k >= 1; k >>= 1) mx = fmaxf(mx, __shfl_xor(mx, k, 64));
  float inv = (mx > 0.f) ? __fdividef(127.f, mx) : 0.f;
  wq[(size_t)wave_g * 64 + lane] = pack4_(v, inv);
  if (lane == 0) wsc[wave_g] = (mx > 0.f) ? (mx / (127.f * 127.f)) : 0.f;
}

// ---------------------------------------------------------------------------
// Kernel A: projected embedding tables. M-tile 128.
// Stored at out[m*2048 + dir*1024 + u*4 + gate]  ([row][dir][unit][i,f,g,o]).
// ---------------------------------------------------------------------------
__global__ __launch_bounds__(256) void proj_gemm(
    const float* __restrict__ A, int rowsA, int Kdim, int col_off,
    const float* __restrict__ wf, const float* __restrict__ wb,
    const float* __restrict__ bf1, const float* __restrict__ bf2,
    const float* __restrict__ bb1, const float* __restrict__ bb2,
    __hip_bfloat16* __restrict__ out, int add_bias) {
  __shared__ __align__(16) __hip_bfloat16 As[128][40];
  __shared__ __align__(16) __hip_bfloat16 Bs[256][40];
  const int tid = threadIdx.x;
  const int m0 = blockIdx.x * 128, n0 = blockIdx.y * 256;
  const int lane = tid & 63, wave = tid >> 6;
  const int quad = lane >> 4, lm = lane & 15;
  float4v acc[2][16] = {};
  const int ksteps = (Kdim + 31) >> 5;
  const int r2 = tid >> 1, cbase = (tid & 1) << 4;
  const int rb = tid >> 4, cb = (tid & 15) * 2;
  for (int ks = 0; ks < ksteps; ++ks) {
    const int k0 = ks << 5;
#pragma unroll
    for (int e2 = 0; e2 < 8; ++e2) {
      int kk = k0 + cbase + 2 * e2;
      float b0 = 0.f, b1 = 0.f;
      if (m0 + r2 < rowsA && kk < Kdim) {
        float2 v = *(const float2*)(A + (size_t)(m0 + r2) * Kdim + kk);
        b0 = v.x;
        b1 = v.y;
      }
      As[r2][cbase + 2 * e2] = __float2bfloat16(b0);
      As[r2][cbase + 2 * e2 + 1] = __float2bfloat16(b1);
    }
#pragma unroll
    for (int j = 0; j < 16; ++j) {
      int n = n0 + rb + 16 * j;
      const float* __restrict__ wrow =
          (n < 1024) ? (wf + n * 450 + col_off) : (wb + (n - 1024) * 450 + col_off);
      int kk = k0 + cb;
      float b0 = 0.f, b1 = 0.f;
      if (kk < Kdim) {
        float2 v = *(const float2*)(wrow + kk);
        b0 = v.x;
        b1 = v.y;
      }
      Bs[rb + 16 * j][cb] = __float2bfloat16(b0);
      Bs[rb + 16 * j][cb + 1] = __float2bfloat16(b1);
    }
    __syncthreads();
    short8 af0 = *(const short8*)(&As[wave * 32 + lm][quad * 8]);
    short8 af1 = *(const short8*)(&As[wave * 32 + 16 + lm][quad * 8]);
#pragma unroll
    for (int t = 0; t < 16; ++t) {
      short8 bf = *(const short8*)(&Bs[t * 16 + lm][quad * 8]);
      acc[0][t] = __builtin_amdgcn_mfma_f32_16x16x32_bf16(af0, bf, acc[0][t], 0, 0, 0);
      acc[1][t] = __builtin_amdgcn_mfma_f32_16x16x32_bf16(af1, bf, acc[1][t], 0, 0, 0);
    }
    __syncthreads();
  }
#pragma unroll
  for (int mg = 0; mg < 2; ++mg) {
#pragma unroll
    for (int t = 0; t < 16; ++t) {
#pragma unroll
      for (int rr = 0; rr < 4; ++rr) {
        int m = m0 + wave * 32 + mg * 16 + quad * 4 + rr;
        int col = n0 + t * 16 + lm;
        if (m < rowsA) {
          float v = acc[mg][t][rr];
          if (add_bias)
            v += (col < 1024) ? (bf1[col] + bf2[col]) : (bb1[col - 1024] + bb2[col - 1024]);
          int dir = col >> 10, rq = col & 1023;
          int gate = rq >> 8, u = rq & 255;
          out[m * 2048 + dir * 1024 + u * 4 + gate] = __float2bfloat16(v);
        }
      }
    }
  }
}

// ---------------------------------------------------------------------------
// Kernel B: BiLSTM recurrence, int8 dot4, 256 threads/chain (4 waves).
// 12 rows int8 in VGPRs (192 regs), 4 rows in conflict-free LDS planes.
// R13: weights LAUNDERED through LDS with an opaque read-slot. The ds_read
// may-alias all later LDS writes (plane fill + per-step hist writes), so the
// compiler can neither forward the store, sink the read into the loop, nor
// rematerialize the values -- they MUST stay register-resident (R11/R12: the
// plain global loads were sunk into the loop: VGPR=132, ~48 L2 loads/step at
// 1 wave/SIMD = unhidden latency, asm "+v" pin was a no-op).
// ---------------------------------------------------------------------------
__global__ __launch_bounds__(256) void lstm_kernel(
    const unsigned int* __restrict__ wq, const float* __restrict__ wsc,
    const int* __restrict__ x, const int* __restrict__ ptags, const int* __restrict__ gtags,
    const char* __restrict__ char_proj, const char* __restrict__ pin_proj,
    const char* __restrict__ tag_proj, __hip_bfloat16* __restrict__ h_out) {
  extern __shared__ __align__(16) char smem[];
  uint4* wlds = (uint4*)smem;                              // 16*256*16 = 65536
  __hip_bfloat16* hist = (__hip_bfloat16*)(smem + 65536);  // 32*256*2 = 16384
  signed char* hb = (signed char*)(smem + 81920);          // 2*256 = 512

  const int tid = threadIdx.x;
  const int q = tid >> 2, e = tid & 3;
  const int chain = blockIdx.x;
  const int dir = chain >> 7;
  const int b = chain & 127;
  const int boff = b * 512;

  if (tid < 32) ((int4*)hb)[tid] = make_int4(0, 0, 0, 0);

  // opaque read-slot: equals tid at runtime, unprovable at compile time
  int rslot = tid;
  asm volatile("" : "+v"(rslot));

  const unsigned int* __restrict__ wqd = wq + (size_t)dir * 65536;
  const float* __restrict__ wscd = wsc + dir * 1024;
  unsigned int Wreg[12][16];
  float sc4[4];
#pragma unroll
  for (int rr = 0; rr < 16; ++rr) {
    const int grow = (rr & 3) * 256 + 4 * q + (rr >> 2);
    const uint4* __restrict__ srcp = (const uint4*)(wqd + grow * 64 + e * 16);
    if ((rr >> 2) == e) sc4[rr & 3] = wscd[grow];
    if (rr < 12) {
      // launder: write own slots, read back via opaque slot (same-thread DS
      // ops are in-order; values become non-rematerializable)
      wlds[tid] = srcp[0];
      wlds[256 + tid] = srcp[1];
      wlds[512 + tid] = srcp[2];
      wlds[768 + tid] = srcp[3];
      uint4 a = wlds[rslot];
      uint4 b4 = wlds[256 + rslot];
      uint4 c4 = wlds[512 + rslot];
      uint4 d4 = wlds[768 + rslot];
      Wreg[rr][0] = a.x;  Wreg[rr][1] = a.y;  Wreg[rr][2] = a.z;  Wreg[rr][3] = a.w;
      Wreg[rr][4] = b4.x; Wreg[rr][5] = b4.y; Wreg[rr][6] = b4.z; Wreg[rr][7] = b4.w;
      Wreg[rr][8] = c4.x; Wreg[rr][9] = c4.y; Wreg[rr][10] = c4.z; Wreg[rr][11] = c4.w;
      Wreg[rr][12] = d4.x; Wreg[rr][13] = d4.y; Wreg[rr][14] = d4.z; Wreg[rr][15] = d4.w;
    } else {
#pragma unroll
      for (int c = 0; c < 4; ++c) wlds[((rr - 12) * 4 + c) * 256 + tid] = srcp[c];
    }
  }
  // launder the 4 dequant scales through the hist region (clobbered in-loop)
  {
    float* fl = (float*)hist;
#pragma unroll
    for (int g = 0; g < 4; ++g) {
      fl[tid] = sc4[g];
      sc4[g] = fl[rslot];
    }
  }
  __syncthreads();

  const int myu = tid;
  const int pre_off = dir * 2048 + myu * 8;
  float cst = 0.f;
  const uint4* wbase = wlds + tid;  // + (p*4+c)*256 becomes a DS imm offset

  // prefetch rotation: indices 2 steps ahead (scalar), gathers 1 step ahead
  int t_cur = dir ? 511 : 0;
  int t_nxt = dir ? 510 : 1;
  int xc = x[boff + t_cur], pc_i = ptags[boff + t_cur], gc_i = gtags[boff + t_cur];
  uint2 vc = *(const uint2*)(char_proj + (size_t)xc * 4096 + pre_off);
  uint2 vp = *(const uint2*)(pin_proj + (size_t)pc_i * 4096 + pre_off);
  uint2 vg = *(const uint2*)(tag_proj + (size_t)gc_i * 4096 + pre_off);
  int xn = x[boff + t_nxt], pn = ptags[boff + t_nxt], gn = gtags[boff + t_nxt];

  for (int s = 0; s < 512; ++s) {
    const int t = t_cur;
    const uint2 cv = vc, pv = vp, gv = vg;
    const int t_fut = dir ? (t_nxt > 0 ? t_nxt - 1 : 0) : (t_nxt < 511 ? t_nxt + 1 : 511);
    vc = *(const uint2*)(char_proj + (size_t)xn * 4096 + pre_off);
    vp = *(const uint2*)(pin_proj + (size_t)pn * 4096 + pre_off);
    vg = *(const uint2*)(tag_proj + (size_t)gn * 4096 + pre_off);
    xn = x[boff + t_fut];
    pn = ptags[boff + t_fut];
    gn = gtags[boff + t_fut];

    const signed char* hbase = hb + (s & 1) * 256 + e * 64;
    int acc[16] = {0, 0, 0, 0, 0, 0, 0, 0, 0, 0, 0, 0, 0, 0, 0, 0};
#pragma unroll
    for (int c = 0; c < 4; ++c) {
      uint4 H = *(const uint4*)(hbase + c * 16);
#pragma unroll
      for (int rr = 0; rr < 12; ++rr) {
        acc[rr] = DOT4(Wreg[rr][4 * c + 0], H.x, acc[rr]);
        acc[rr] = DOT4(Wreg[rr][4 * c + 1], H.y, acc[rr]);
        acc[rr] = DOT4(Wreg[rr][4 * c + 2], H.z, acc[rr]);
        acc[rr] = DOT4(Wreg[rr][4 * c + 3], H.w, acc[rr]);
      }
#pragma unroll
      for (int p = 0; p < 4; ++p) {
        uint4 wv = wbase[(p * 4 + c) * 256];
        acc[12 + p] = DOT4(wv.x, H.x, acc[12 + p]);
        acc[12 + p] = DOT4(wv.y, H.y, acc[12 + p]);
        acc[12 + p] = DOT4(wv.z, H.z, acc[12 + p]);
        acc[12 + p] = DOT4(wv.w, H.w, acc[12 + p]);
      }
    }
#pragma unroll
    for (int rr = 0; rr < 16; ++rr) {
      int v = qadd_i<XOR1>(acc[rr]);
      acc[rr] = qadd_i<XOR2>(v);
    }
    int ai = e == 0 ? acc[0] : (e == 1 ? acc[4] : (e == 2 ? acc[8] : acc[12]));
    int af = e == 0 ? acc[1] : (e == 1 ? acc[5] : (e == 2 ? acc[9] : acc[13]));
    int ag = e == 0 ? acc[2] : (e == 1 ? acc[6] : (e == 2 ? acc[10] : acc[14]));
    int ao = e == 0 ? acc[3] : (e == 1 ? acc[7] : (e == 2 ? acc[11] : acc[15]));
    float gi = bflo(cv.x) + bflo(pv.x) + bflo(gv.x) + (float)ai * sc4[0];
    float gf = bfhi(cv.x) + bfhi(pv.x) + bfhi(gv.x) + (float)af * sc4[1];
    float gg = bflo(cv.y) + bflo(pv.y) + bflo(gv.y) + (float)ag * sc4[2];
    float go = bfhi(cv.y) + bfhi(pv.y) + bfhi(gv.y) + (float)ao * sc4[3];
    cst = sigmoidf_(gf) * cst + sigmoidf_(gi) * tanhf_(gg);
    float hval = sigmoidf_(go) * tanhf_(cst);
    hb[((s + 1) & 1) * 256 + myu] = (signed char)(int)rintf(hval * 127.f);
    hist[(s & 31) * 256 + myu] = __float2bfloat16(hval);
    barrier_lgkm();
    if ((s & 15) == 15) {
      const int slotBase = (s & 31) & ~15;
      const int sBase = s - 15;
#pragma unroll
      for (int i = 0; i < 2; ++i) {
        int c = i * 256 + tid;
        int row = c >> 5;
        int col16 = c & 31;
        uint4 v = *(const uint4*)((const char*)hist + (slotBase + row) * 512 + col16 * 16);
        int step_r = sBase + row;
        int t_r = dir ? (511 - step_r) : step_r;
        *(uint4*)((char*)h_out + ((size_t)(chain * 512 + t_r) * 256) * 2 + col16 * 16) = v;
      }
    }
    t_cur = t_nxt;
    t_nxt = t_fut;
  }
}

// ---------------------------------------------------------------------------
// Kernel C: emissions GEMM. em[b*512+t][k] = Hcat[n]·w_out[k] + b_out[k]
// ---------------------------------------------------------------------------
__global__ __launch_bounds__(256) void emis_kernel(
    const __hip_bfloat16* __restrict__ h_glob, const float* __restrict__ w_out,
    const float* __restrict__ b_out, float* __restrict__ em) {
  __shared__ __align__(16) __hip_bfloat16 As[64][40];
  __shared__ __align__(16) __hip_bfloat16 Bs[32][40];
  const int tid = threadIdx.x;
  const int n0 = blockIdx.x * 64;
  const int lane = tid & 63, wave = tid >> 6, quad = lane >> 4, lm = lane & 15;
  float4v acc[2] = {};
  const int r = tid >> 2, c0 = (tid & 3) << 3;
  const int rb = tid >> 3, cb = (tid & 7) << 2;
  for (int ks = 0; ks < 16; ++ks) {
    const int j0 = ks * 32;
    const int dirk = j0 >> 8, jin = j0 & 255;
    const int n = n0 + r, bb = n >> 9, tt = n & 511;
    const uint4* src =
        (const uint4*)(h_glob + ((size_t)(dirk * 128 + bb) * 512 + tt) * 256 + jin + c0);
    *(uint4*)(&As[r][c0]) = *src;
#pragma unroll
    for (int e = 0; e < 4; ++e) {
      float v = (rb < 20) ? w_out[rb * 512 + j0 + cb + e] : 0.f;
      Bs[rb][cb + e] = __float2bfloat16(v);
    }
    __syncthreads();
    short8 af = *(const short8*)(&As[wave * 16 + lm][quad * 8]);
#pragma unroll
    for (int t2 = 0; t2 < 2; ++t2) {
      short8 bf = *(const short8*)(&Bs[t2 * 16 + lm][quad * 8]);
      acc[t2] = __builtin_amdgcn_mfma_f32_16x16x32_bf16(af, bf, acc[t2], 0, 0, 0);
    }
    __syncthreads();
  }
#pragma unroll
  for (int t2 = 0; t2 < 2; ++t2) {
#pragma unroll
    for (int rr = 0; rr < 4; ++rr) {
      int col = t2 * 16 + lm;
      if (col < 20) {
        int n = n0 + wave * 16 + quad * 4 + rr;
        em[(size_t)n * 20 + col] = acc[t2][rr] + b_out[col];
      }
    }
  }
}

// ---------------------------------------------------------------------------
// Kernel D: CRF forward NLL. 1 wave per batch element, readlane broadcast.
// ---------------------------------------------------------------------------
__global__ __launch_bounds__(64) void crf_kernel(
    const float* __restrict__ em, const int* __restrict__ y,
    const float* __restrict__ start_trans, const float* __restrict__ end_trans,
    const float* __restrict__ trans, float* __restrict__ partials) {
  const int b = blockIdx.x;
  const int lane = threadIdx.x;
  const int jj = lane < 20 ? lane : 19;
  const bool act = lane < 20;
  const float* __restrict__ emb = em + (size_t)b * 512 * 20;
  const int* __restrict__ yb = y + b * 512;

  float s_part = 0.f;
#pragma unroll
  for (int i = 0; i < 8; ++i) {
    int t = lane + 64 * i;
    int yc = yb[t];
    float v = emb[t * 20 + yc];
    v += (t == 0) ? start_trans[yc] : trans[yb[t - 1] * 20 + yc];
    s_part += v;
  }
#pragma unroll
  for (int k = 32; k >= 1; k >>= 1) s_part += __shfl_xor(s_part, k, 64);
  float score = s_part + end_trans[yb[511]];

  float ET[20];
#pragma unroll
  for (int i = 0; i < 20; ++i) ET[i] = __expf(trans[i * 20 + jj]);
  float alpha = act ? (start_trans[jj] + emb[jj]) : -1e30f;
  float P = alpha;
#pragma unroll
  for (int k = 32; k >= 1; k >>= 1) P = fmaxf(P, __shfl_xor(P, k, 64));

  float eC = emb[1 * 20 + jj];
  float eN = emb[2 * 20 + jj];
  for (int t = 1; t < 512; ++t) {
    if ((t & 15) == 0) {
      P = alpha;
#pragma unroll
      for (int k = 32; k >= 1; k >>= 1) P = fmaxf(P, __shfl_xor(P, k, 64));
    }
    float ex = __expf(alpha - P);
    float s0 = 0.f, s1 = 0.f;
#pragma unroll
    for (int i = 0; i < 20; i += 2) {
      float e0 = __int_as_float(__builtin_amdgcn_readlane(__float_as_int(ex), i));
      float e1 = __int_as_float(__builtin_amdgcn_readlane(__float_as_int(ex), i + 1));
      s0 = fmaf(e0, ET[i], s0);
      s1 = fmaf(e1, ET[i + 1], s1);
    }
    int tf = t + 2 < 512 ? t + 2 : 511;
    float eF = emb[tf * 20 + jj];
    if (act) alpha = P + __logf(s0 + s1) + eC;
    eC = eN;
    eN = eF;
  }
  float v = act ? (alpha + end_trans[jj]) : -1e30f;
  float Pz = v;
#pragma unroll
  for (int k = 32; k >= 1; k >>= 1) Pz = fmaxf(Pz, __shfl_xor(Pz, k, 64));
  float e2 = __expf(v - Pz);
#pragma unroll
  for (int k = 32; k >= 1; k >>= 1) e2 += __shfl_xor(e2, k, 64);
  float logZ = Pz + __logf(e2);
  if (lane == 0) partials[b] = logZ - score;
}

__global__ __launch_bounds__(128) void reduce_kernel(const float* __restrict__ partials,
                                                     float* __restrict__ out) {
  const int tid = threadIdx.x;
  float v = partials[tid];
#pragma unroll
  for (int k = 32; k >= 1; k >>= 1) v += __shfl_xor(v, k, 64);
  __shared__ float tmp[2];
  if ((tid & 63) == 0) tmp[tid >> 6] = v;
  __syncthreads();
  if (tid == 0) out[0] = tmp[0] + tmp[1];
}

// ---------------------------------------------------------------------------
extern "C" void kernel_launch(void* const* d_in, const int* in_sizes, int n_in,
                              void* d_out, int out_size, void* d_ws, size_t ws_size,
                              hipStream_t stream) {
  const int* x = (const int*)d_in[0];
  const int* y = (const int*)d_in[1];
  const int* pre_tags = (const int*)d_in[2];
  const int* pinyin_tags = (const int*)d_in[3];
  const float* char_emb = (const float*)d_in[5];
  const float* tag_emb = (const float*)d_in[6];
  const float* pinyin_emb = (const float*)d_in[7];
  const float* w_ih_f = (const float*)d_in[8];
  const float* w_hh_f = (const float*)d_in[9];
  const float* b_ih_f = (const float*)d_in[10];
  const float* b_hh_f = (const float*)d_in[11];
  const float* w_ih_b = (const float*)d_in[12];
  const float* w_hh_b = (const float*)d_in[13];
  const float* b_ih_b = (const float*)d_in[14];
  const float* b_hh_b = (const float*)d_in[15];
  const float* w_out = (const float*)d_in[16];
  const float* b_out = (const float*)d_in[17];
  const float* start_trans = (const float*)d_in[18];
  const float* end_trans = (const float*)d_in[19];
  const float* trans = (const float*)d_in[20];

  char* ws = (char*)d_ws;
  __hip_bfloat16* char_proj = (__hip_bfloat16*)(ws);            // 10002*2048*2 = 40968192
  __hip_bfloat16* pin_proj = (__hip_bfloat16*)(ws + 40968192);  // 500*2048*2  = 2048000
  __hip_bfloat16* tag_proj = (__hip_bfloat16*)(ws + 43016192);  // 20*2048*2   = 81920
  __hip_bfloat16* h_glob = (__hip_bfloat16*)(ws + 43098112);    // 2*128*512*256*2 = 67108864
  float* em = (float*)(ws + 110206976);                         // 65536*20*4 = 5242880
  float* partials = (float*)(ws + 115449856);                   // 128*4
  // wq/wsc live inside the em region (em is written only after lstm finishes)
  unsigned int* wq = (unsigned int*)(ws + 110206976);           // 2*1024*64*4 = 524288
  float* wsc = (float*)(ws + 110206976 + 524288);               // 2048*4

  wquant_kernel<<<512, 256, 0, stream>>>(w_hh_f, w_hh_b, wq, wsc);

  proj_gemm<<<dim3(79, 8), 256, 0, stream>>>(char_emb, 10002, 300, 0, w_ih_f, w_ih_b,
                                             nullptr, nullptr, nullptr, nullptr, char_proj, 0);
  proj_gemm<<<dim3(4, 8), 256, 0, stream>>>(pinyin_emb, 500, 100, 300, w_ih_f, w_ih_b,
                                            nullptr, nullptr, nullptr, nullptr, pin_proj, 0);
  proj_gemm<<<dim3(1, 8), 256, 0, stream>>>(tag_emb, 20, 50, 400, w_ih_f, w_ih_b,
                                            b_ih_f, b_hh_f, b_ih_b, b_hh_b, tag_proj, 1);

  const int lstm_lds = 82432;  // 65536 planes + 16384 hist + 512 hbuf
  hipFuncSetAttribute((const void*)lstm_kernel, hipFuncAttributeMaxDynamicSharedMemorySize,
                      lstm_lds);
  lstm_kernel<<<256, 256, lstm_lds, stream>>>(wq, wsc, x, pinyin_tags, pre_tags,
                                              (const char*)char_proj, (const char*)pin_proj,
                                              (const char*)tag_proj, h_glob);

  emis_kernel<<<1024, 256, 0, stream>>>(h_glob, w_out, b_out, em);
  crf_kernel<<<128, 64, 0, stream>>>(em, y, start_trans, end_trans, trans, partials);
  reduce_kernel<<<1, 128, 0, stream>>>(partials, (float*)d_out);
}